// Round 1
// baseline (4177.354 us; speedup 1.0000x reference)
//
#include <hip/hip_runtime.h>
#include <math.h>

#define TLEN 256
#define NB   32
#define HID  512
#define VOC  1024

// ---------------- GEMM: logits = enc @ W^T + bias ----------------
// A: (T*B, H) row-major; W: (V, H) row-major; C: (T*B, V)
__global__ __launch_bounds__(256) void gemm_logits(
    const float* __restrict__ A, const float* __restrict__ W,
    const float* __restrict__ bias, float* __restrict__ C)
{
    const int N = VOC, K = HID;
    __shared__ float As[64][17];
    __shared__ float Ws[64][17];
    int tid = threadIdx.x;
    int row0 = blockIdx.y * 64;
    int col0 = blockIdx.x * 64;
    int tx = tid & 15, ty = tid >> 4;
    float acc[4][4] = {};
    int lr = tid >> 2;           // 0..63
    int lk = (tid & 3) << 2;     // 0,4,8,12
    for (int k0 = 0; k0 < K; k0 += 16) {
        float4 av = *(const float4*)(A + (size_t)(row0 + lr) * K + k0 + lk);
        float4 wv = *(const float4*)(W + (size_t)(col0 + lr) * K + k0 + lk);
        As[lr][lk+0]=av.x; As[lr][lk+1]=av.y; As[lr][lk+2]=av.z; As[lr][lk+3]=av.w;
        Ws[lr][lk+0]=wv.x; Ws[lr][lk+1]=wv.y; Ws[lr][lk+2]=wv.z; Ws[lr][lk+3]=wv.w;
        __syncthreads();
        #pragma unroll
        for (int k = 0; k < 16; ++k) {
            float a[4], w[4];
            #pragma unroll
            for (int i = 0; i < 4; ++i) a[i] = As[ty*4+i][k];
            #pragma unroll
            for (int j = 0; j < 4; ++j) w[j] = Ws[tx*4+j][k];
            #pragma unroll
            for (int i = 0; i < 4; ++i)
                #pragma unroll
                for (int j = 0; j < 4; ++j)
                    acc[i][j] = fmaf(a[i], w[j], acc[i][j]);
        }
        __syncthreads();
    }
    #pragma unroll
    for (int i = 0; i < 4; ++i) {
        int r = row0 + ty*4 + i;
        #pragma unroll
        for (int j = 0; j < 4; ++j) {
            int cc = col0 + tx*4 + j;
            C[(size_t)r * N + cc] = acc[i][j] + bias[cc];
        }
    }
}

// ---------------- E = exp(transition), elementwise ----------------
__global__ __launch_bounds__(256) void exp_kernel(
    const float* __restrict__ in, float* __restrict__ out, int n4)
{
    int i = blockIdx.x * 256 + threadIdx.x;
    if (i < n4) {
        float4 v = ((const float4*)in)[i];
        float4 r;
        r.x = __expf(v.x); r.y = __expf(v.y); r.z = __expf(v.z); r.w = __expf(v.w);
        ((float4*)out)[i] = r;
    }
}

// ---------------- one CRF forward step ----------------
// Z_new[b,c] = logit_t[b,c] + m_b + log( sum_v exp(Z[b,v]-m_b) * E[v,c] )
// grid: (VOC/64 col-chunks, NB/4 batch-groups); block 256 = 4 waves, wave bl = batch b
__global__ __launch_bounds__(256) void crf_step(
    const float* __restrict__ Zsrc, float* __restrict__ Zdst,
    const float* __restrict__ E, const float* __restrict__ logit_t,
    const int* __restrict__ lengths, int t)
{
    __shared__ __align__(16) float ps[4][VOC];
    int tid  = threadIdx.x;
    int bl   = tid >> 6;        // wave index = local batch
    int lane = tid & 63;
    int b    = blockIdx.y * 4 + bl;
    int c    = blockIdx.x * 64 + lane;
    const float* zrow = Zsrc + (size_t)b * VOC;
    float zold = zrow[c];
    int len = lengths[b];
    if (t >= len) {             // wave-uniform branch: sequence finished, copy through
        Zdst[(size_t)b * VOC + c] = zold;
        return;
    }
    // wave-wide max over Z[b,:]
    float zv[16];
    float m = -1e30f;
    #pragma unroll
    for (int i = 0; i < 16; ++i) { zv[i] = zrow[lane + (i << 6)]; m = fmaxf(m, zv[i]); }
    #pragma unroll
    for (int off = 32; off > 0; off >>= 1) m = fmaxf(m, __shfl_xor(m, off));
    // p = exp(Z - m) into this wave's private LDS row (wave-coherent, no barrier needed)
    #pragma unroll
    for (int i = 0; i < 16; ++i) ps[bl][lane + (i << 6)] = __expf(zv[i] - m);
    // S[c] = sum_v p[v] * E[v,c]   (p broadcast from LDS, E coalesced per wave)
    float s0 = 0.f, s1 = 0.f, s2 = 0.f, s3 = 0.f;
    const float* Ec = E + c;
    #pragma unroll 4
    for (int v = 0; v < VOC; v += 4) {
        float4 p4 = *(const float4*)&ps[bl][v];
        s0 = fmaf(p4.x, Ec[(size_t)(v + 0) << 10], s0);
        s1 = fmaf(p4.y, Ec[(size_t)(v + 1) << 10], s1);
        s2 = fmaf(p4.z, Ec[(size_t)(v + 2) << 10], s2);
        s3 = fmaf(p4.w, Ec[(size_t)(v + 3) << 10], s3);
    }
    float S = (s0 + s1) + (s2 + s3);
    Zdst[(size_t)b * VOC + c] = logit_t[(size_t)b * VOC + c] + m + __logf(S);
}

// ---------------- epilogue: log_Z, emit score, trans score, mean ----------------
__global__ __launch_bounds__(256) void crf_finish(
    const float* __restrict__ Zfin, const float* __restrict__ logits,
    const float* __restrict__ trans, const int* __restrict__ targets,
    const int* __restrict__ lengths, float* __restrict__ out)
{
    __shared__ float part[NB];
    int tid = threadIdx.x;
    int b = tid >> 3, j = tid & 7;   // 8 threads per batch
    const float* zr = Zfin + (size_t)b * VOC;
    float m = -1e30f;
    for (int v = j; v < VOC; v += 8) m = fmaxf(m, zr[v]);
    #pragma unroll
    for (int off = 1; off < 8; off <<= 1) m = fmaxf(m, __shfl_xor(m, off));
    float s = 0.f;
    for (int v = j; v < VOC; v += 8) s += __expf(zr[v] - m);
    #pragma unroll
    for (int off = 1; off < 8; off <<= 1) s += __shfl_xor(s, off);
    float logZ = m + __logf(s);
    int len = lengths[b];
    float acc = 0.f;
    for (int t = j; t < TLEN; t += 8) {
        if (t < len) {
            int tg = targets[t * NB + b];
            acc += logits[((size_t)t * NB + b) * VOC + tg];
            if (t >= 1) acc += trans[(size_t)targets[(t - 1) * NB + b] * VOC + tg];
        }
    }
    #pragma unroll
    for (int off = 1; off < 8; off <<= 1) acc += __shfl_xor(acc, off);
    if (j == 0) part[b] = logZ - acc;
    __syncthreads();
    if (tid == 0) {
        float sum = 0.f;
        #pragma unroll
        for (int i = 0; i < NB; ++i) sum += part[i];
        out[0] = sum / (float)NB;
    }
}

extern "C" void kernel_launch(void* const* d_in, const int* in_sizes, int n_in,
                              void* d_out, int out_size, void* d_ws, size_t ws_size,
                              hipStream_t stream)
{
    const float* enc   = (const float*)d_in[0];   // (T,B,H)
    const float* W     = (const float*)d_in[1];   // (V,H)
    const float* bias  = (const float*)d_in[2];   // (V,)
    const float* trans = (const float*)d_in[3];   // (V,V)
    const int* targets = (const int*)d_in[4];     // (T,B)
    const int* lengths = (const int*)d_in[5];     // (B,)
    float* out = (float*)d_out;

    // workspace layout (floats): logits 8.39M | E 1.05M | Za 32K | Zb 32K  (~38 MB)
    float* ws     = (float*)d_ws;
    float* logits = ws;
    float* E      = logits + (size_t)TLEN * NB * VOC;
    float* Za     = E + (size_t)VOC * VOC;
    float* Zb     = Za + (size_t)NB * VOC;

    gemm_logits<<<dim3(VOC / 64, TLEN * NB / 64), 256, 0, stream>>>(enc, W, bias, logits);
    exp_kernel<<<dim3((VOC * VOC / 4 + 255) / 256), 256, 0, stream>>>(trans, E, VOC * VOC / 4);

    const float* src = logits;                    // Z0 = logits[t=0] = first 32 rows
    for (int t = 1; t < TLEN; ++t) {
        float* dst = (t & 1) ? Za : Zb;
        crf_step<<<dim3(VOC / 64, NB / 4), 256, 0, stream>>>(
            src, dst, E, logits + (size_t)t * NB * VOC, lengths, t);
        src = dst;
    }
    crf_finish<<<1, 256, 0, stream>>>(src, logits, trans, targets, lengths, out);
}

// Round 2
// 1774.818 us; speedup vs baseline: 2.3537x; 2.3537x over previous
//
#include <hip/hip_runtime.h>
#include <math.h>

#define TLEN 256
#define NB   32
#define HID  512
#define VOC  1024

// ---------------- GEMM v2: logits = enc @ W^T + bias ----------------
// A: (T*B, H) row-major; W: (V, H) row-major; C: (T*B, V)
// 128x128 tile, BK=16, 256 threads, 8x8 microtile, k-major LDS for b128 reads.
__global__ __launch_bounds__(256) void gemm_logits2(
    const float* __restrict__ A, const float* __restrict__ W,
    const float* __restrict__ bias, float* __restrict__ C)
{
    const int K = HID, N = VOC;
    __shared__ float As[16][132];   // [k][row], pad 4
    __shared__ float Ws[16][132];   // [k][col]
    int tid = threadIdx.x;
    int row0 = blockIdx.y << 7;
    int col0 = blockIdx.x << 7;
    int tx = tid & 15, ty = tid >> 4;       // 16x16 grid of 8x8 microtiles
    int lr = tid >> 2;                      // 0..63
    int lk = (tid & 3) << 2;                // 0,4,8,12
    float acc[8][8] = {};
    float bj[8];
    #pragma unroll
    for (int j = 0; j < 8; ++j) bj[j] = bias[col0 + tx * 8 + j];

    for (int k0 = 0; k0 < K; k0 += 16) {
        float4 av0 = *(const float4*)(A + (size_t)(row0 + lr) * K + k0 + lk);
        float4 av1 = *(const float4*)(A + (size_t)(row0 + lr + 64) * K + k0 + lk);
        float4 wv0 = *(const float4*)(W + (size_t)(col0 + lr) * K + k0 + lk);
        float4 wv1 = *(const float4*)(W + (size_t)(col0 + lr + 64) * K + k0 + lk);
        __syncthreads();   // protect previous iteration's LDS reads
        As[lk+0][lr] = av0.x; As[lk+1][lr] = av0.y; As[lk+2][lr] = av0.z; As[lk+3][lr] = av0.w;
        As[lk+0][lr+64] = av1.x; As[lk+1][lr+64] = av1.y; As[lk+2][lr+64] = av1.z; As[lk+3][lr+64] = av1.w;
        Ws[lk+0][lr] = wv0.x; Ws[lk+1][lr] = wv0.y; Ws[lk+2][lr] = wv0.z; Ws[lk+3][lr] = wv0.w;
        Ws[lk+0][lr+64] = wv1.x; Ws[lk+1][lr+64] = wv1.y; Ws[lk+2][lr+64] = wv1.z; Ws[lk+3][lr+64] = wv1.w;
        __syncthreads();
        #pragma unroll
        for (int k = 0; k < 16; ++k) {
            float4 a0 = *(const float4*)&As[k][ty * 8];
            float4 a1 = *(const float4*)&As[k][ty * 8 + 4];
            float4 w0 = *(const float4*)&Ws[k][tx * 8];
            float4 w1 = *(const float4*)&Ws[k][tx * 8 + 4];
            float ar[8] = {a0.x, a0.y, a0.z, a0.w, a1.x, a1.y, a1.z, a1.w};
            float wr[8] = {w0.x, w0.y, w0.z, w0.w, w1.x, w1.y, w1.z, w1.w};
            #pragma unroll
            for (int i = 0; i < 8; ++i)
                #pragma unroll
                for (int j = 0; j < 8; ++j)
                    acc[i][j] = fmaf(ar[i], wr[j], acc[i][j]);
        }
    }
    #pragma unroll
    for (int i = 0; i < 8; ++i) {
        size_t r = row0 + ty * 8 + i;
        float4 o0, o1;
        o0.x = acc[i][0] + bj[0]; o0.y = acc[i][1] + bj[1];
        o0.z = acc[i][2] + bj[2]; o0.w = acc[i][3] + bj[3];
        o1.x = acc[i][4] + bj[4]; o1.y = acc[i][5] + bj[5];
        o1.z = acc[i][6] + bj[6]; o1.w = acc[i][7] + bj[7];
        *(float4*)(C + r * N + col0 + tx * 8)     = o0;
        *(float4*)(C + r * N + col0 + tx * 8 + 4) = o1;
    }
}

// ---------------- E = exp(transition), elementwise ----------------
__global__ __launch_bounds__(256) void exp_kernel(
    const float* __restrict__ in, float* __restrict__ out, int n4)
{
    int i = blockIdx.x * 256 + threadIdx.x;
    if (i < n4) {
        float4 v = ((const float4*)in)[i];
        float4 r;
        r.x = __expf(v.x); r.y = __expf(v.y); r.z = __expf(v.z); r.w = __expf(v.w);
        ((float4*)out)[i] = r;
    }
}

// ---------------- one CRF forward step (v2) ----------------
// Z_new[b,c] = logit_t[b,c] + m_b + log( sum_v exp(Z[b,v]-m_b) * E[v,c] )
// grid (16,8): 16 col-chunks x 8 batch-groups(4 batches). 512 thr = 8 waves = 8 v-chunks.
// p staged TRANSPOSED in LDS: pst[v][bl] so one b128 broadcast gives p for 4 batches.
__global__ __launch_bounds__(512) void crf_step2(
    const float* __restrict__ Zsrc, float* __restrict__ Zdst,
    const float* __restrict__ E, const float* __restrict__ logit_t,
    const int* __restrict__ lengths, int t)
{
    __shared__ __align__(16) float pst[VOC][4];  // 16 KB
    __shared__ float m4[4];
    __shared__ int   len4[4];
    __shared__ float Sred[8][64][5];             // padded: +1 breaks 4-stride conflicts
    int tid  = threadIdx.x;
    int w    = tid >> 6;
    int lane = tid & 63;
    int cc   = blockIdx.x;
    int bg   = blockIdx.y;

    // stage p for the 4 batches (waves 0..3)
    if (w < 4) {
        int b = bg * 4 + w;
        const float* zrow = Zsrc + b * VOC;
        float zv[16];
        float m = -1e30f;
        #pragma unroll
        for (int i = 0; i < 16; ++i) { zv[i] = zrow[lane + (i << 6)]; m = fmaxf(m, zv[i]); }
        #pragma unroll
        for (int off = 32; off; off >>= 1) m = fmaxf(m, __shfl_xor(m, off));
        #pragma unroll
        for (int i = 0; i < 16; ++i) pst[lane + (i << 6)][w] = __expf(zv[i] - m);
        if (lane == 0) { m4[w] = m; len4[w] = lengths[b]; }
    }
    __syncthreads();

    int lmax = max(max(len4[0], len4[1]), max(len4[2], len4[3]));
    int c = (cc << 6) + lane;
    if (t >= lmax) {                 // block-uniform: all 4 batches finished -> copy
        if (w < 4) {
            int b = bg * 4 + w;
            Zdst[b * VOC + c] = Zsrc[b * VOC + c];
        }
        return;
    }

    // wave w: partial S over v in [w*128, w*128+128) for 64 cols x 4 batches
    const float* Ec = E + c;
    float a0 = 0.f, a1 = 0.f, a2 = 0.f, a3 = 0.f;
    int v0 = w << 7;
    #pragma unroll 4
    for (int vv = 0; vv < 128; vv += 4) {
        int v = v0 + vv;
        float e0 = Ec[(size_t)(v + 0) << 10];
        float e1 = Ec[(size_t)(v + 1) << 10];
        float e2 = Ec[(size_t)(v + 2) << 10];
        float e3 = Ec[(size_t)(v + 3) << 10];
        float4 p0 = *(const float4*)&pst[v + 0][0];   // wave-uniform -> broadcast
        float4 p1 = *(const float4*)&pst[v + 1][0];
        float4 p2 = *(const float4*)&pst[v + 2][0];
        float4 p3 = *(const float4*)&pst[v + 3][0];
        a0 = fmaf(e0, p0.x, a0); a1 = fmaf(e0, p0.y, a1); a2 = fmaf(e0, p0.z, a2); a3 = fmaf(e0, p0.w, a3);
        a0 = fmaf(e1, p1.x, a0); a1 = fmaf(e1, p1.y, a1); a2 = fmaf(e1, p1.z, a2); a3 = fmaf(e1, p1.w, a3);
        a0 = fmaf(e2, p2.x, a0); a1 = fmaf(e2, p2.y, a1); a2 = fmaf(e2, p2.z, a2); a3 = fmaf(e2, p2.w, a3);
        a0 = fmaf(e3, p3.x, a0); a1 = fmaf(e3, p3.y, a1); a2 = fmaf(e3, p3.z, a2); a3 = fmaf(e3, p3.w, a3);
    }
    Sred[w][lane][0] = a0;
    Sred[w][lane][1] = a1;
    Sred[w][lane][2] = a2;
    Sred[w][lane][3] = a3;
    __syncthreads();

    // finalize: threads 0..255, b-major for coalesced stores
    if (tid < 256) {
        int bl = tid >> 6;
        int cl = tid & 63;
        float S = 0.f;
        #pragma unroll
        for (int ww = 0; ww < 8; ++ww) S += Sred[ww][cl][bl];
        int b  = bg * 4 + bl;
        int cg = (cc << 6) + cl;
        float out;
        if (t < len4[bl]) out = logit_t[b * VOC + cg] + m4[bl] + __logf(S);
        else              out = Zsrc[b * VOC + cg];
        Zdst[b * VOC + cg] = out;
    }
}

// ---------------- epilogue: log_Z, emit score, trans score, mean ----------------
__global__ __launch_bounds__(256) void crf_finish(
    const float* __restrict__ Zfin, const float* __restrict__ logits,
    const float* __restrict__ trans, const int* __restrict__ targets,
    const int* __restrict__ lengths, float* __restrict__ out)
{
    __shared__ float part[NB];
    int tid = threadIdx.x;
    int b = tid >> 3, j = tid & 7;   // 8 threads per batch
    const float* zr = Zfin + (size_t)b * VOC;
    float m = -1e30f;
    for (int v = j; v < VOC; v += 8) m = fmaxf(m, zr[v]);
    #pragma unroll
    for (int off = 1; off < 8; off <<= 1) m = fmaxf(m, __shfl_xor(m, off));
    float s = 0.f;
    for (int v = j; v < VOC; v += 8) s += __expf(zr[v] - m);
    #pragma unroll
    for (int off = 1; off < 8; off <<= 1) s += __shfl_xor(s, off);
    float logZ = m + __logf(s);
    int len = lengths[b];
    float acc = 0.f;
    for (int t = j; t < TLEN; t += 8) {
        if (t < len) {
            int tg = targets[t * NB + b];
            acc += logits[((size_t)t * NB + b) * VOC + tg];
            if (t >= 1) acc += trans[(size_t)targets[(t - 1) * NB + b] * VOC + tg];
        }
    }
    #pragma unroll
    for (int off = 1; off < 8; off <<= 1) acc += __shfl_xor(acc, off);
    if (j == 0) part[b] = logZ - acc;
    __syncthreads();
    if (tid == 0) {
        float sum = 0.f;
        #pragma unroll
        for (int i = 0; i < NB; ++i) sum += part[i];
        out[0] = sum / (float)NB;
    }
}

extern "C" void kernel_launch(void* const* d_in, const int* in_sizes, int n_in,
                              void* d_out, int out_size, void* d_ws, size_t ws_size,
                              hipStream_t stream)
{
    const float* enc   = (const float*)d_in[0];   // (T,B,H)
    const float* W     = (const float*)d_in[1];   // (V,H)
    const float* bias  = (const float*)d_in[2];   // (V,)
    const float* trans = (const float*)d_in[3];   // (V,V)
    const int* targets = (const int*)d_in[4];     // (T,B)
    const int* lengths = (const int*)d_in[5];     // (B,)
    float* out = (float*)d_out;

    // workspace layout (floats): logits 8.39M | E 1.05M | Za 32K | Zb 32K  (~38 MB)
    float* ws     = (float*)d_ws;
    float* logits = ws;
    float* E      = logits + (size_t)TLEN * NB * VOC;
    float* Za     = E + (size_t)VOC * VOC;
    float* Zb     = Za + (size_t)NB * VOC;

    gemm_logits2<<<dim3(VOC / 128, TLEN * NB / 128), 256, 0, stream>>>(enc, W, bias, logits);
    exp_kernel<<<dim3((VOC * VOC / 4 + 255) / 256), 256, 0, stream>>>(trans, E, VOC * VOC / 4);

    const float* src = logits;                    // Z0 = logits[t=0]
    for (int t = 1; t < TLEN; ++t) {
        float* dst = (t & 1) ? Za : Zb;
        crf_step2<<<dim3(16, 8), 512, 0, stream>>>(
            src, dst, E, logits + (size_t)t * NB * VOC, lengths, t);
        src = dst;
    }
    crf_finish<<<1, 256, 0, stream>>>(src, logits, trans, targets, lengths, out);
}